// Round 1
// baseline (714.260 us; speedup 1.0000x reference)
//
#include <hip/hip_runtime.h>
#include <hip/hip_bf16.h>
#include <math.h>

#define NSEG 1024
#define HID  256      // x feature dim
#define H2   128      // hidden dim (W1 cols)
#define TM   32       // rows per tile
#define LROW 260      // padded floats per LDS row (1040 B: bank advance 4/row)

typedef __attribute__((ext_vector_type(8))) __bf16 bf16x8;
typedef __attribute__((ext_vector_type(4))) float  f32x4;

__device__ __forceinline__ bf16x8 pack8(f32x4 lo, f32x4 hi) {
    bf16x8 b;
    b[0] = (__bf16)lo[0]; b[1] = (__bf16)lo[1]; b[2] = (__bf16)lo[2]; b[3] = (__bf16)lo[3];
    b[4] = (__bf16)hi[0]; b[5] = (__bf16)hi[1]; b[6] = (__bf16)hi[2]; b[7] = (__bf16)hi[3];
    return b;
}

// One block per segment. 256 threads = 4 waves.
// Wave w owns hidden cols [w*32, w*32+32): 2 n-tiles of 16.
// Per 32-row tile: h = x_tile @ W1 via MFMA (2 m-tiles x 2 n-tiles x 8 k-tiles),
// scores reduced cross-lane + cross-wave, then online-softmax weighted
// accumulation where thread t owns output dim t.
__global__ __launch_bounds__(256, 2)
void attn_pool_kernel(const float* __restrict__ x, const int* __restrict__ batch,
                      const float* __restrict__ W1, const float* __restrict__ b1,
                      const float* __restrict__ W2, float* __restrict__ out, int N)
{
    __shared__ __align__(16) float xs[2][TM * LROW];   // 2 x 32.5 KB, f32 x tiles
    __shared__ float s_part[4][TM];
    __shared__ float s_fin[TM];

    const int tid  = threadIdx.x;
    const int wid  = tid >> 6;
    const int lane = tid & 63;
    const int l15  = lane & 15;
    const int lg   = lane >> 4;          // 0..3
    const int seg  = blockIdx.x;

    // segment bounds: batch is sorted ascending
    int lo = 0, hi = N;
    while (lo < hi) { int mid = (lo + hi) >> 1; if (batch[mid] < seg) lo = mid + 1; else hi = mid; }
    const int start = lo;
    hi = N;
    while (lo < hi) { int mid = (lo + hi) >> 1; if (batch[mid] <= seg) lo = mid + 1; else hi = mid; }
    const int end = lo;

    // ---- W1 -> per-wave bf16 B-fragments in registers (reused for all tiles) ----
    // B-frag layout (16x16x32): lane holds B[k = kt*32 + lg*8 + j][col = nt*16 + l15]
    bf16x8 bfrag[8][2];
    #pragma unroll
    for (int kt = 0; kt < 8; ++kt) {
        #pragma unroll
        for (int nt = 0; nt < 2; ++nt) {
            const int col = wid * 32 + nt * 16 + l15;
            const int kb  = kt * 32 + lg * 8;
            bf16x8 b;
            #pragma unroll
            for (int j = 0; j < 8; ++j) b[j] = (__bf16)W1[(kb + j) * H2 + col];
            bfrag[kt][nt] = b;
        }
    }
    float b1v[2], w2v[2];
    #pragma unroll
    for (int nt = 0; nt < 2; ++nt) {
        const int col = wid * 32 + nt * 16 + l15;
        b1v[nt] = b1[col];
        w2v[nt] = W2[col];
    }

    float m_run = -INFINITY, l_run = 0.f, acc_d = 0.f;

    const int cnt    = end - start;
    const int ntiles = (cnt + TM - 1) / TM;

    f32x4 st[8];   // staging regs: 32 floats/thread = one 32x256 tile per block

    if (ntiles > 0) {   // prologue: stage tile 0
        #pragma unroll
        for (int q = 0; q < 8; ++q) {
            int idx = q * 256 + tid;            // float4 index in 32x256 tile
            int r = idx >> 6, c4 = idx & 63;
            int gr = start + r; if (gr > end - 1) gr = end - 1;   // clamp tail rows
            st[q] = *(const f32x4*)&x[gr * HID + c4 * 4];
        }
        #pragma unroll
        for (int q = 0; q < 8; ++q) {
            int idx = q * 256 + tid;
            int r = idx >> 6, c4 = idx & 63;
            *(f32x4*)&xs[0][r * LROW + c4 * 4] = st[q];
        }
    }
    __syncthreads();

    for (int t = 0; t < ntiles; ++t) {
        const int  cur      = t & 1;
        const int  row0     = start + t * TM;
        const bool has_next = (t + 1) < ntiles;
        const float* xb     = xs[cur];

        // issue next tile's global loads NOW; LDS write happens after compute (T14)
        if (has_next) {
            const int nrow0 = row0 + TM;
            #pragma unroll
            for (int q = 0; q < 8; ++q) {
                int idx = q * 256 + tid;
                int r = idx >> 6, c4 = idx & 63;
                int gr = nrow0 + r; if (gr > end - 1) gr = end - 1;
                st[q] = *(const f32x4*)&x[gr * HID + c4 * 4];
            }
        }

        // ---- h = x_tile @ W1 (bf16 MFMA, f32 accum) ----
        f32x4 acc[2][2] = {};
        #pragma unroll
        for (int kt = 0; kt < 8; ++kt) {
            bf16x8 a[2];
            #pragma unroll
            for (int mt = 0; mt < 2; ++mt) {
                // A-frag: lane holds A[row = mt*16 + l15][k = kt*32 + lg*8 + j]
                const float* p = &xb[(mt * 16 + l15) * LROW + kt * 32 + lg * 8];
                f32x4 lo4 = *(const f32x4*)p;
                f32x4 hi4 = *(const f32x4*)(p + 4);
                a[mt] = pack8(lo4, hi4);
            }
            #pragma unroll
            for (int mt = 0; mt < 2; ++mt)
                #pragma unroll
                for (int nt = 0; nt < 2; ++nt)
                    acc[mt][nt] = __builtin_amdgcn_mfma_f32_16x16x32_bf16(
                        a[mt], bfrag[kt][nt], acc[mt][nt], 0, 0, 0);
        }

        // ---- scores: s = sum_j tanh(h + b1) * W2 ----
        // C/D layout: col = l15, row = lg*4 + r (verified m89)
        #pragma unroll
        for (int mt = 0; mt < 2; ++mt) {
            #pragma unroll
            for (int r = 0; r < 4; ++r) {
                float p = 0.f;
                #pragma unroll
                for (int nt = 0; nt < 2; ++nt) {
                    float h  = acc[mt][nt][r] + b1v[nt];
                    float e2 = __expf(fminf(2.f * h, 80.f));
                    float th = __fdividef(e2 - 1.f, e2 + 1.f);
                    p = fmaf(th, w2v[nt], p);
                }
                // reduce over the 16 lanes (l15) holding the same row
                p += __shfl_xor(p, 1);
                p += __shfl_xor(p, 2);
                p += __shfl_xor(p, 4);
                p += __shfl_xor(p, 8);
                if (l15 == 0) s_part[wid][mt * 16 + lg * 4 + r] = p;
            }
        }
        __syncthreads();
        if (tid < TM) {
            float s = s_part[0][tid] + s_part[1][tid] + s_part[2][tid] + s_part[3][tid];
            if (row0 + tid >= end) s = -1e30f;   // mask tail rows
            s_fin[tid] = s;
        }
        __syncthreads();

        // ---- online softmax + weighted accumulation (thread owns dim tid) ----
        float tmax = -1e30f;
        #pragma unroll
        for (int i = 0; i < TM; ++i) tmax = fmaxf(tmax, s_fin[i]);
        const float m_new = fmaxf(m_run, tmax);
        const float scale = __expf(m_run - m_new);   // m_run=-inf first tile -> 0
        acc_d *= scale;
        l_run *= scale;
        #pragma unroll
        for (int i = 0; i < TM; ++i) {
            float e = __expf(s_fin[i] - m_new);      // masked rows -> exp(-1e30)=0
            l_run += e;
            acc_d  = fmaf(e, xb[i * LROW + tid], acc_d);
        }
        m_run = m_new;

        // write staged regs into the other buffer, then barrier
        if (has_next) {
            #pragma unroll
            for (int q = 0; q < 8; ++q) {
                int idx = q * 256 + tid;
                int r = idx >> 6, c4 = idx & 63;
                *(f32x4*)&xs[cur ^ 1][r * LROW + c4 * 4] = st[q];
            }
        }
        __syncthreads();
    }

    // empty segment: 0 / 1e-8 = 0, matches segment_sum over empty set
    out[seg * HID + tid] = acc_d / (l_run + 1e-8f);
}

extern "C" void kernel_launch(void* const* d_in, const int* in_sizes, int n_in,
                              void* d_out, int out_size, void* d_ws, size_t ws_size,
                              hipStream_t stream) {
    const float* x     = (const float*)d_in[0];
    const int*   batch = (const int*)d_in[1];
    const float* W1    = (const float*)d_in[2];
    const float* b1    = (const float*)d_in[3];
    const float* W2    = (const float*)d_in[4];
    // d_in[5] = b2: uniform shift, cancels in the segment softmax — unused.
    float* out = (float*)d_out;
    const int N = in_sizes[1];   // number of nodes (batch length)

    attn_pool_kernel<<<NSEG, 256, 0, stream>>>(x, batch, W1, b1, W2, out, N);
}